// Round 1
// 403.626 us; speedup vs baseline: 1.0319x; 1.0319x over previous
//
#include <hip/hip_runtime.h>
#include <hip/hip_fp16.h>
#include <math.h>

// ---------------------------------------------------------------------------
// Net_37512244363273: 5-level edge-conditioned graph conv + voxel pooling + FC
// Round 16: latency-parallelism pass. Poles (countA 49us, scanP3 47us) were
// small-grid latency-bound (occ 9.8-18.6%, all pipes idle). Changes:
//  - seg0/seg1 tiles 4096->1024 edges (TILES0=1024, TILES1=256): 4x blocks in
//    cnt0/part0/part1; colscan0 scans 4 tiles/thread, colscan1 full 256-scan.
//  - segs 2-9 hist/scatter de-bucketed: 170 blocks of 1024 elems, one device
//    atomic per element, no 8x tile re-read.
//  - hstats K 32->8 (170 blocks); fast exp-based tanh everywhere.
//  - conv0c: single streaming pass, 7 LDS float atomicAdds per record into
//    nacc[7][128] (bank-spread), replaces hist+scan+idxL sort + serial gather.
//  - long-running roles ordered first within each fused kernel.
// Still 16 dispatches. Output: 80 log_softmax + closs = 81 floats.
// ---------------------------------------------------------------------------

#define TILES0 1024                // seg0 tiles (1024 edges each)
#define TSZ0   1024
#define NB0    512                 // seg0 buckets (dst>>7, 128 nodes each)
#define TILES1 256                 // seg1 tiles (1024 edges each)
#define TSZ1   1024
#define NB1    512                 // seg1 buckets (dst>>5, 32 nodes each)

__device__ __forceinline__ float ftanh(float x) {
    // tanh(x) = 1 - 2/(e^{2x}+1); exact at +-inf, ~1e-7 abs err (tol 7.8e-3)
    float e = __expf(2.f * x);
    return 1.f - 2.f / (e + 1.f);
}

struct SegArgs {
    const int* idx[10];
    int*       cnt[10];
    int*       rp [10];
    int*       out[10];
    int        n  [10];
    int        nb [10];
    int        tstart[11];
};

struct ScanAux {
    int* tilesum;
    int* tileoff;
    int  sstart[11];
    int  T;
};

struct HArgs {
    const float* eattr[5];
    const float* w1[5];
    const float* b1[5];
    float*       H;
    int          E[5];
    int          bstart[6];
};

struct WArgs {
    const float* w2[5];
    const float* b2[5];
    const float* H;
    float*       sq;
    int          cico[5];
    int          E[5];
};

// ---------------------------------------------------------------------------
// K2: countA = cnt0 (1024) | cnt1 (256) | hstats (hsBlocks) | hist (tiles)
// ---------------------------------------------------------------------------
__global__ __launch_bounds__(256) void countA_k(
    SegArgs a, HArgs ha, const int* __restrict__ dst0,
    const int* __restrict__ dst1, int* __restrict__ M, int* __restrict__ M1,
    int hsBlocks)
{
    __shared__ int sh[NB0];
    int B = blockIdx.x;
    int t = threadIdx.x;

    if (B < TILES0) {                              // ---- cnt0 ----
        for (int u = t; u < NB0; u += 256) sh[u] = 0;
        __syncthreads();
        int base = B * TSZ0 + t;
        #pragma unroll
        for (int it = 0; it < 4; it++)
            atomicAdd(&sh[dst0[base + it * 256] >> 7], 1);
        __syncthreads();
        for (int u = t; u < NB0; u += 256) M[(size_t)B * NB0 + u] = sh[u];
        return;
    }
    B -= TILES0;
    if (B < TILES1) {                              // ---- cnt1 ----
        for (int u = t; u < NB1; u += 256) sh[u] = 0;
        __syncthreads();
        int base = B * TSZ1 + t;
        #pragma unroll
        for (int it = 0; it < 4; it++)
            atomicAdd(&sh[dst1[base + it * 256] >> 5], 1);
        __syncthreads();
        for (int u = t; u < NB1; u += 256) M1[(size_t)B * NB1 + u] = sh[u];
        return;
    }
    B -= TILES1;
    if (B < hsBlocks) {                            // ---- hstats (levels 1-4) ----
        const int K = 8;
        int l = 0;
        while (l < 4 && B >= ha.bstart[l + 1]) l++;
        int bloc = B - ha.bstart[l];
        const float* ea = ha.eattr[l];
        float w1r[15], b1r[5];
        #pragma unroll
        for (int i = 0; i < 15; i++) w1r[i] = ha.w1[l][i];
        #pragma unroll
        for (int i = 0; i < 5; i++)  b1r[i] = ha.b1[l][i];
        float acc[20];
        #pragma unroll
        for (int i = 0; i < 20; i++) acc[i] = 0.f;
        int base = bloc * 256 * K + t;
        for (int it = 0; it < K; it++) {
            int e = base + it * 256;
            if (e < ha.E[l]) {
                float e0 = ea[e * 3], e1 = ea[e * 3 + 1], e2 = ea[e * 3 + 2];
                float h[5];
                #pragma unroll
                for (int k = 0; k < 5; k++)
                    h[k] = ftanh(e0 * w1r[k] + e1 * w1r[5 + k] + e2 * w1r[10 + k] + b1r[k]);
                int p = 5;
                #pragma unroll
                for (int k = 0; k < 5; k++) {
                    acc[k] += h[k];
                    #pragma unroll
                    for (int k2 = k; k2 < 5; k2++) acc[p++] += h[k] * h[k2];
                }
            }
        }
        float* red = (float*)sh;
        int wid = t >> 6, lane = t & 63;
        #pragma unroll
        for (int v = 0; v < 20; v++) {
            float s = acc[v];
            #pragma unroll
            for (int o = 32; o; o >>= 1) s += __shfl_down(s, o);
            if (lane == 0) red[wid * 20 + v] = s;
        }
        __syncthreads();
        if (t < 20)
            atomicAdd(&ha.H[l * 20 + t],
                      red[t] + red[20 + t] + red[40 + t] + red[60 + t]);
        return;
    }
    B -= hsBlocks;
    {                                              // ---- hist (segs 2-9) ----
        int s = 0;
        while (s < 9 && B >= a.tstart[s + 1]) s++;
        int i0 = (B - a.tstart[s]) * 1024;
        const int* idx = a.idx[s];
        int* cnt = a.cnt[s];
        int n = a.n[s];
        #pragma unroll
        for (int j = 0; j < 4; j++) {
            int i = i0 + j * 256 + t;
            if (i < n) atomicAdd(&cnt[idx[i]], 1);
        }
    }
}

// ---------------------------------------------------------------------------
// K3: scanP1 = colscan0 (NB0) | colscan1 (NB1) | scanA (rest)
// ---------------------------------------------------------------------------
__global__ __launch_bounds__(256) void scanP1_k(
    SegArgs a, ScanAux x, const int* __restrict__ M, int* __restrict__ M2,
    int* __restrict__ colTotal, const int* __restrict__ M1,
    int* __restrict__ M21, int* __restrict__ ct1)
{
    __shared__ int sc[256];
    int B = blockIdx.x;
    int t = threadIdx.x;

    if (B < NB0) {                                 // ---- colscan0 (4 tiles/thr) ----
        int v[4];
        int s4 = 0;
        #pragma unroll
        for (int j = 0; j < 4; j++) {
            v[j] = M[(size_t)(t * 4 + j) * NB0 + B];
            s4 += v[j];
        }
        sc[t] = s4;
        __syncthreads();
        for (int d = 1; d < 256; d <<= 1) {
            int u = (t >= d) ? sc[t - d] : 0;
            __syncthreads();
            sc[t] += u;
            __syncthreads();
        }
        int run = sc[t] - s4;
        #pragma unroll
        for (int j = 0; j < 4; j++) {
            M2[(size_t)(t * 4 + j) * NB0 + B] = run;
            run += v[j];
        }
        if (t == 255) colTotal[B] = sc[255];
        return;
    }
    B -= NB0;
    if (B < NB1) {                                 // ---- colscan1 (256 tiles) ----
        int v = M1[(size_t)t * NB1 + B];
        sc[t] = v;
        __syncthreads();
        for (int d = 1; d < 256; d <<= 1) {
            int u = (t >= d) ? sc[t - d] : 0;
            __syncthreads();
            sc[t] += u;
            __syncthreads();
        }
        M21[(size_t)t * NB1 + B] = sc[t] - v;
        if (t == 255) ct1[B] = sc[255];
        return;
    }
    // ---- scanA (segs 2-9) ----
    int b = B - NB1;
    int s = 0;
    while (s < 9 && b >= x.sstart[s + 1]) s++;
    int tloc = b - x.sstart[s];
    int nb = a.nb[s];
    const int* cnt = a.cnt[s];
    int i0 = tloc * 4096 + t * 16;
    int sum = 0;
    #pragma unroll
    for (int k = 0; k < 16; k++) {
        int i = i0 + k;
        if (i < nb) sum += cnt[i];
    }
    #pragma unroll
    for (int o = 32; o; o >>= 1) sum += __shfl_down(sum, o);
    if ((t & 63) == 0) sc[t >> 6] = sum;
    __syncthreads();
    if (t == 0)
        x.tilesum[b] = sc[0] + sc[1] + sc[2] + sc[3];
}

// ---------------------------------------------------------------------------
// K4: scanP2 = bktscan0 (blk 0) | scanB (blk 1) | bktscan1 (blk 2)
// ---------------------------------------------------------------------------
__global__ __launch_bounds__(512) void scanP2_k(
    SegArgs a, ScanAux x, const int* __restrict__ colTotal,
    int* __restrict__ bucketStart, const int* __restrict__ ct1,
    int* __restrict__ bs1)
{
    __shared__ int sc[NB0];
    int t = threadIdx.x;
    if (blockIdx.x == 0) {                         // ---- bktscan0 ----
        int v = colTotal[t];
        sc[t] = v;
        __syncthreads();
        for (int d = 1; d < NB0; d <<= 1) {
            int u = (t >= d) ? sc[t - d] : 0;
            __syncthreads();
            sc[t] += u;
            __syncthreads();
        }
        bucketStart[t] = sc[t] - v;
        if (t == NB0 - 1) bucketStart[NB0] = sc[NB0 - 1];
        return;
    }
    if (blockIdx.x == 2) {                         // ---- bktscan1 ----
        int v = ct1[t];
        sc[t] = v;
        __syncthreads();
        for (int d = 1; d < NB1; d <<= 1) {
            int u = (t >= d) ? sc[t - d] : 0;
            __syncthreads();
            sc[t] += u;
            __syncthreads();
        }
        bs1[t] = sc[t] - v;
        if (t == NB1 - 1) bs1[NB1] = sc[NB1 - 1];
        return;
    }
    // ---- scanB (wave 0) ----
    if (t >= 64) return;
    int lane = t;
    int orig = (lane < x.T) ? x.tilesum[lane] : 0;
    int val = orig;
    #pragma unroll
    for (int d = 1; d < 64; d <<= 1) {
        int v = __shfl_up(val, d);
        if (lane >= d) val += v;
    }
    int excl = val - orig;
    int s = 0;
    while (s < 9 && lane >= x.sstart[s + 1]) s++;
    int segExcl = __shfl(excl, x.sstart[s]);
    if (lane < x.T) {
        x.tileoff[lane] = excl - segExcl;
        if (lane == x.sstart[s + 1] - 1)
            a.rp[s][a.nb[s]] = val - segExcl;
    }
}

// ---------------------------------------------------------------------------
// K5: scanP3 = part0 (TILES0) | part1 (TILES1) | scanC (sx.T)
// ---------------------------------------------------------------------------
__global__ __launch_bounds__(256) void scanP3_k(
    SegArgs a, ScanAux x,
    const int* __restrict__ src, const int* __restrict__ dst,
    const float* __restrict__ ea, const float* __restrict__ x0,
    const int* __restrict__ M2, const int* __restrict__ bucketStart,
    float4* __restrict__ pay2,
    const float* __restrict__ w1, const float* __restrict__ b1,
    float* __restrict__ H0,
    const int* __restrict__ src1, const int* __restrict__ dst1,
    const float* __restrict__ ea1, const int* __restrict__ M21,
    const int* __restrict__ bs1, float4* __restrict__ pay1)
{
    __shared__ int   shi[NB0];
    __shared__ float shf[100];
    int B = blockIdx.x;
    int t = threadIdx.x;

    if (B < TILES0) {                              // ---- part0 ----
        int tile = B;
        for (int u = t; u < NB0; u += 256)
            shi[u] = bucketStart[u] + M2[(size_t)tile * NB0 + u];
        if (t < 15) shf[t] = w1[t];
        if (t >= 32 && t < 37) shf[15 + t - 32] = b1[t - 32];
        __syncthreads();

        float acc[20];
        #pragma unroll
        for (int i = 0; i < 20; i++) acc[i] = 0.f;

        int base = tile * TSZ0 + t;
        #pragma unroll
        for (int it = 0; it < 4; it++) {
            int i = base + it * 256;
            int d = dst[i];
            float e0 = ea[i * 3], e1 = ea[i * 3 + 1], e2 = ea[i * 3 + 2];
            float h[5];
            #pragma unroll
            for (int k = 0; k < 5; k++)
                h[k] = ftanh(e0 * shf[k] + e1 * shf[5 + k] + e2 * shf[10 + k] + shf[15 + k]);
            int p = 5;
            #pragma unroll
            for (int k = 0; k < 5; k++) {
                acc[k] += h[k];
                #pragma unroll
                for (int k2 = k; k2 < 5; k2++) acc[p++] += h[k] * h[k2];
            }
            float xv = x0[src[i]];
            union HU { __half2 h2; float f; } p01, p23;
            p01.h2 = __floats2half2_rn(h[0], h[1]);
            p23.h2 = __floats2half2_rn(h[2], h[3]);
            unsigned wbits = ((unsigned)d << 16) |
                             (unsigned)__half_as_ushort(__float2half_rn(h[4]));
            int ps = atomicAdd(&shi[d >> 7], 1);
            pay2[ps] = make_float4(xv, p01.f, p23.f, __uint_as_float(wbits));
        }

        int wid = t >> 6, lane = t & 63;
        #pragma unroll
        for (int v = 0; v < 20; v++) {
            float s = acc[v];
            #pragma unroll
            for (int o = 32; o; o >>= 1) s += __shfl_down(s, o);
            if (lane == 0) shf[20 + wid * 20 + v] = s;
        }
        __syncthreads();
        if (t < 20)
            atomicAdd(&H0[t], shf[20 + t] + shf[40 + t] + shf[60 + t] + shf[80 + t]);
        return;
    }
    B -= TILES0;
    if (B < TILES1) {                              // ---- part1 ----
        int tile = B;
        for (int u = t; u < NB1; u += 256)
            shi[u] = bs1[u] + M21[(size_t)tile * NB1 + u];
        __syncthreads();
        int base = tile * TSZ1 + t;
        #pragma unroll
        for (int it = 0; it < 4; it++) {
            int i = base + it * 256;
            int d = dst1[i];
            int key = (d << 16) | src1[i];
            float e0 = ea1[i * 3], e1 = ea1[i * 3 + 1], e2 = ea1[i * 3 + 2];
            int ps = atomicAdd(&shi[d >> 5], 1);
            pay1[ps] = make_float4(__int_as_float(key), e0, e1, e2);
        }
        return;
    }
    // ---- scanC (segs 2-9) ----
    B -= TILES1;
    int s = 0;
    while (s < 9 && B >= x.sstart[s + 1]) s++;
    int tloc = B - x.sstart[s];
    int nb = a.nb[s];
    const int* cnt = a.cnt[s];
    int* rp = a.rp[s];
    int i0 = tloc * 4096 + t * 16;
    int v[16];
    int sum = 0;
    #pragma unroll
    for (int k = 0; k < 16; k++) {
        int i = i0 + k;
        v[k] = (i < nb) ? cnt[i] : 0;
        sum += v[k];
    }
    int acc = sum;
    shi[t] = acc;
    __syncthreads();
    for (int d = 1; d < 256; d <<= 1) {
        int t2 = (t >= d) ? shi[t - d] : 0;
        __syncthreads();
        acc += t2;
        shi[t] = acc;
        __syncthreads();
    }
    int running = x.tileoff[B] + (acc - sum);
    #pragma unroll
    for (int k = 0; k < 16; k++) {
        int i = i0 + k;
        if (i < nb) rp[i] = running;
        running += v[k];
    }
}

// ---------------------------------------------------------------------------
// K6: scatC = conv0c (NB0) | bucket1 (NB1) | wstats (5) | scatter (tiles)
// conv0c: single streaming pass; 7 LDS float atomics/record into nacc[7][128]
// (slot = k*128+node so each instruction's lanes spread across banks).
// ---------------------------------------------------------------------------
__global__ __launch_bounds__(256) void scatC_k(
    SegArgs a, WArgs wa,
    const float4* __restrict__ pay2, const int* __restrict__ bucketStart,
    const float* __restrict__ w2, const float* __restrict__ b2,
    const float* __restrict__ root, const float* __restrict__ bias,
    const float* __restrict__ x, float* __restrict__ y,
    const float4* __restrict__ pay1, const int* __restrict__ bs1,
    int* __restrict__ rp1, float4* __restrict__ rec1)
{
    __shared__ float wsm[96];
    __shared__ float nacc[7 * 128];
    __shared__ int hist[32], st[32], cur[32];
    int B = blockIdx.x;
    int t = threadIdx.x;

    if (B < NB0) {                                 // ---- conv0c ----
        if (t < 60) wsm[t] = w2[t];
        else if (t >= 64  && t < 76)  wsm[60 + t - 64]  = b2[t - 64];
        else if (t >= 128 && t < 140) wsm[72 + t - 128] = root[t - 128];
        else if (t >= 192 && t < 204) wsm[84 + t - 192] = bias[t - 192];
        for (int u = t; u < 7 * 128; u += 256) nacc[u] = 0.f;
        __syncthreads();

        int lo = bucketStart[B], hi = bucketStart[B + 1];
        int bin0 = B << 7;
        for (int j = lo + t; j < hi; j += 256) {
            float4 R = pay2[j];
            union HU { float f; __half2 h2; } a01, a23;
            a01.f = R.y; a23.f = R.z;
            unsigned wbits = __float_as_uint(R.w);
            int node = (int)(wbits >> 16) - bin0;
            float xv = R.x;
            atomicAdd(&nacc[node], xv);
            atomicAdd(&nacc[128 + node], __low2float(a01.h2)  * xv);
            atomicAdd(&nacc[256 + node], __high2float(a01.h2) * xv);
            atomicAdd(&nacc[384 + node], __low2float(a23.h2)  * xv);
            atomicAdd(&nacc[512 + node], __high2float(a23.h2) * xv);
            atomicAdd(&nacc[640 + node],
                      __half2float(__ushort_as_half((unsigned short)(wbits & 0xffffu))) * xv);
            atomicAdd(&nacc[768 + node], 1.f);
        }
        __syncthreads();

        if (t < 128) {
            int v = bin0 + t;
            float deg = nacc[768 + t];
            float S0 = nacc[t],       S1 = nacc[128 + t], S2 = nacc[256 + t];
            float S3 = nacc[384 + t], S4 = nacc[512 + t], S5 = nacc[640 + t];
            float inv = 1.f / fmaxf(deg, 1.f);
            float xv = x[v];
            #pragma unroll
            for (int o = 0; o < 12; o++) {
                float msg = wsm[60 + o] * S0 + wsm[o] * S1 + wsm[12 + o] * S2 +
                            wsm[24 + o] * S3 + wsm[36 + o] * S4 + wsm[48 + o] * S5;
                y[v * 12 + o] = msg * inv + xv * wsm[72 + o] + wsm[84 + o];
            }
        }
        return;
    }
    B -= NB0;
    if (B < NB1) {                                 // ---- bucket1 ----
        int b = B;
        int lo = bs1[b], hi = bs1[b + 1];
        int bin0 = b << 5;
        if (t < 32) hist[t] = 0;
        __syncthreads();
        const float* payw = (const float*)pay1;
        for (int j = lo + t; j < hi; j += 256) {
            int rel = (int)(__float_as_uint(payw[4 * j]) >> 16) - bin0;
            atomicAdd(&hist[rel], 1);
        }
        __syncthreads();
        if (t < 32) {                              // wave-level exclusive scan
            int v = hist[t];
            int val = v;
            #pragma unroll
            for (int d = 1; d < 32; d <<= 1) {
                int u = __shfl_up(val, d);
                if (t >= d) val += u;
            }
            st[t] = val - v;
            cur[t] = lo + val - v;
            rp1[bin0 + t] = lo + val - v;
            if (b == NB1 - 1 && t == 31) rp1[NB1 * 32] = hi;
        }
        __syncthreads();
        for (int j = lo + t; j < hi; j += 256) {
            float4 R = pay1[j];
            int rel = (int)(__float_as_uint(R.x) >> 16) - bin0;
            int p = atomicAdd(&cur[rel], 1);
            rec1[p] = R;
        }
        return;
    }
    B -= NB1;
    if (B < 5) {                                   // ---- wstats (wave 0) ----
        if (t >= 64) return;
        int l = B;
        const float* w2l = wa.w2[l];
        const float* b2l = wa.b2[l];
        int cico = wa.cico[l];
        float d[21];
        #pragma unroll
        for (int i = 0; i < 21; i++) d[i] = 0.f;
        for (int u = t; u < cico; u += 64) {
            float b = b2l[u];
            float w[5];
            #pragma unroll
            for (int k = 0; k < 5; k++) w[k] = w2l[k * cico + u];
            int p = 0;
            #pragma unroll
            for (int k = 0; k < 5; k++) {
                #pragma unroll
                for (int k2 = k; k2 < 5; k2++) d[p++] += w[k] * w[k2];
            }
            #pragma unroll
            for (int k = 0; k < 5; k++) d[15 + k] += b * w[k];
            d[20] += b * b;
        }
        #pragma unroll
        for (int i = 0; i < 21; i++) {
            #pragma unroll
            for (int off = 32; off; off >>= 1) d[i] += __shfl_down(d[i], off);
        }
        if (t == 0) {
            const float* H1 = wa.H + l * 20;
            const float* H2 = H1 + 5;
            float sq = (float)wa.E[l] * d[20];
            #pragma unroll
            for (int k = 0; k < 5; k++) sq += 2.f * d[15 + k] * H1[k];
            int p = 0;
            #pragma unroll
            for (int k = 0; k < 5; k++) {
                #pragma unroll
                for (int k2 = k; k2 < 5; k2++) {
                    sq += ((k == k2) ? 1.f : 2.f) * d[p] * H2[p];
                    p++;
                }
            }
            wa.sq[l] = sq;
        }
        return;
    }
    B -= 5;
    {                                              // ---- scatter (segs 2-9) ----
        int s = 0;
        while (s < 9 && B >= a.tstart[s + 1]) s++;
        int i0 = (B - a.tstart[s]) * 1024;
        const int* idx = a.idx[s];
        int* cnt = a.cnt[s];
        const int* rp = a.rp[s];
        int* out = a.out[s];
        int n = a.n[s];
        #pragma unroll
        for (int j = 0; j < 4; j++) {
            int i = i0 + j * 256 + t;
            if (i < n) {
                int d = idx[i];
                int p = atomicSub(&cnt[d], 1) - 1;
                out[rp[d] + p] = i;
            }
        }
    }
}

// ---------------------------------------------------------------------------
// conv1s_k (L1): block per node, streams contiguous dst-sorted records.
// ---------------------------------------------------------------------------
__global__ __launch_bounds__(256) void conv1s_k(
    const int* __restrict__ rp, const float4* __restrict__ rec,
    const float* __restrict__ w1, const float* __restrict__ b1,
    const float* __restrict__ w2, const float* __restrict__ b2,
    const float* __restrict__ root, const float* __restrict__ bias,
    const float* __restrict__ x, float* __restrict__ y)
{
    constexpr int CI = 15, CO = 20, CH = 48, CICO = CI * CO;
    __shared__ float w1s[20];
    __shared__ float4 recb[CH];
    __shared__ int   svb[CH];
    __shared__ float hb[CH * 6];
    __shared__ float xs[CH * CI];
    __shared__ float S[6 * CI];

    int t = threadIdx.x;
    int v = blockIdx.x;
    if (t < 20) w1s[t] = (t < 15) ? w1[t] : b1[t - 15];
    int r0 = rp[v], r1 = rp[v + 1];
    int d  = r1 - r0;
    float acc = 0.f;

    for (int c0 = r0; c0 < r1; c0 += CH) {
        int cn = min(CH, r1 - c0);
        if (t < cn) {
            float4 R = rec[c0 + t];
            recb[t] = R;
            svb[t]  = (int)(__float_as_uint(R.x) & 0xffffu);
            hb[t * 6] = 1.f;
        }
        __syncthreads();
        if (t < cn * 5) {
            int j = t / 5, k = t % 5;
            float e0 = recb[j].y, e1 = recb[j].z, e2 = recb[j].w;
            hb[j * 6 + 1 + k] =
                ftanh(e0 * w1s[k] + e1 * w1s[5 + k] + e2 * w1s[10 + k] + w1s[15 + k]);
        }
        for (int u = t; u < cn * CI; u += 256)
            xs[u] = x[(size_t)svb[u / CI] * CI + (u % CI)];
        __syncthreads();
        if (t < 6 * CI) {
            int i = t / 6, k6 = t % 6;
            for (int j = 0; j < cn; j++)
                acc += hb[j * 6 + k6] * xs[j * CI + i];
        }
        __syncthreads();
    }

    if (t < 6 * CI) S[t] = acc;
    __syncthreads();

    if (t < CO) {
        float m = 0.f;
        for (int i = 0; i < CI; i++) {
            m += b2[i * CO + t] * S[i * 6];
            #pragma unroll
            for (int k = 0; k < 5; k++)
                m += w2[k * CICO + i * CO + t] * S[i * 6 + 1 + k];
        }
        m /= fmaxf((float)d, 1.f);
        for (int i = 0; i < CI; i++)
            m += x[(size_t)v * CI + i] * root[i * CO + t];
        y[(size_t)v * CO + t] = m + bias[t];
    }
}

// ---------------------------------------------------------------------------
// coop_conv_k (L2-L4), pool_k, fc_k
// ---------------------------------------------------------------------------
template<int CI, int CO>
__global__ __launch_bounds__(256) void coop_conv_k(
    const int* __restrict__ rp, const int* __restrict__ eid,
    const int* __restrict__ src, const float* __restrict__ eattr,
    const float* __restrict__ w1, const float* __restrict__ b1,
    const float* __restrict__ w2, const float* __restrict__ b2,
    const float* __restrict__ root, const float* __restrict__ bias,
    const float* __restrict__ x, float* __restrict__ y)
{
    constexpr int CH   = 48;
    constexpr int CICO = CI * CO;
    __shared__ float w1s[20];
    __shared__ int   eb[CH], svb[CH];
    __shared__ float hb[CH * 6];
    __shared__ float xs[CH * CI];
    __shared__ float S[6 * CI];

    int t = threadIdx.x;
    int v = blockIdx.x;
    if (t < 20) w1s[t] = (t < 15) ? w1[t] : b1[t - 15];
    int r0 = rp[v], r1 = rp[v + 1];
    int d  = r1 - r0;
    float acc = 0.f;

    for (int c0 = r0; c0 < r1; c0 += CH) {
        int cn = min(CH, r1 - c0);
        if (t < cn) {
            int e = eid[c0 + t];
            eb[t]  = e;
            svb[t] = src[e];
            hb[t * 6] = 1.f;
        }
        __syncthreads();
        if (t < cn * 5) {
            int j = t / 5, k = t % 5;
            int e = eb[j];
            float e0 = eattr[e * 3], e1 = eattr[e * 3 + 1], e2 = eattr[e * 3 + 2];
            hb[j * 6 + 1 + k] =
                ftanh(e0 * w1s[k] + e1 * w1s[5 + k] + e2 * w1s[10 + k] + w1s[15 + k]);
        }
        for (int u = t; u < cn * CI; u += 256)
            xs[u] = x[(size_t)svb[u / CI] * CI + (u % CI)];
        __syncthreads();
        if (t < 6 * CI) {
            int i = t / 6, k6 = t % 6;
            for (int j = 0; j < cn; j++)
                acc += hb[j * 6 + k6] * xs[j * CI + i];
        }
        __syncthreads();
    }

    if (t < 6 * CI) S[t] = acc;
    __syncthreads();

    if (t < CO) {
        float m = 0.f;
        for (int i = 0; i < CI; i++) {
            m += b2[i * CO + t] * S[i * 6];
            #pragma unroll
            for (int k = 0; k < 5; k++)
                m += w2[k * CICO + i * CO + t] * S[i * 6 + 1 + k];
        }
        m /= fmaxf((float)d, 1.f);
        for (int i = 0; i < CI; i++)
            m += x[(size_t)v * CI + i] * root[i * CO + t];
        y[(size_t)v * CO + t] = m + bias[t];
    }
}

template<int CO>
__global__ __launch_bounds__(256) void pool_k(
    int NN,
    const int* __restrict__ crp, const int* __restrict__ cnid,
    const float* __restrict__ y, const float* __restrict__ pos,
    float* __restrict__ xn, float* __restrict__ pn)
{
    int t = blockIdx.x * 256 + threadIdx.x;
    if (t >= NN * (CO + 3)) return;
    int c = t / (CO + 3), o = t % (CO + 3);
    int r0 = crp[c], r1 = crp[c + 1];
    int d = r1 - r0;
    if (o < CO) {
        float m = -INFINITY;
        for (int j = r0; j < r1; j++)
            m = fmaxf(m, y[(size_t)cnid[j] * CO + o]);
        if (d == 0 || !isfinite(m)) m = 0.f;
        xn[c * (CO + 3) + o] = m;
    } else {
        int k = o - CO;
        float sum = 0.f;
        for (int j = r0; j < r1; j++)
            sum += pos[cnid[j] * 3 + k];
        float pm = sum / fmaxf((float)d, 1.f);
        xn[c * (CO + 3) + CO + k] = pm;
        pn[c * 3 + k] = pm;
    }
}

__global__ __launch_bounds__(128) void fc_k(
    const float* __restrict__ x5,
    const float* __restrict__ fc_w, const float* __restrict__ fc_b,
    const float* __restrict__ sq, float* __restrict__ out)
{
    __shared__ float feat[8 * 376];
    __shared__ float logit[80];
    __shared__ float roff[8];
    for (int t = threadIdx.x; t < 8 * 376; t += 128) feat[t] = x5[t];
    __syncthreads();
    int t = threadIdx.x;
    if (t < 80) {
        int b = t / 10, j = t % 10;
        float acc = fc_b[j];
        for (int k = 0; k < 376; k++) acc += feat[b * 376 + k] * fc_w[k * 10 + j];
        logit[t] = acc;
    }
    __syncthreads();
    if (t < 8) {
        float m = -1e30f;
        for (int j = 0; j < 10; j++) m = fmaxf(m, logit[t * 10 + j]);
        float ssum = 0.f;
        for (int j = 0; j < 10; j++) ssum += expf(logit[t * 10 + j] - m);
        roff[t] = m + logf(ssum);
    }
    __syncthreads();
    if (t < 80) out[t] = logit[t] - roff[t / 10];
    if (t == 0) {
        float closs = 0.f;
        closs += sq[0] * (1.0f / 12582912.0f);
        closs += sq[1] * (1.0f / 78643200.0f);
        closs += sq[2] * (1.0f / 42205184.0f);
        closs += sq[3] * (1.0f / 18284544.0f);
        closs += sq[4] * (1.0f / 7028736.0f);
        out[80] = closs;
    }
}

// ---------------------------------------------------------------------------

extern "C" void kernel_launch(void* const* d_in, const int* in_sizes, int n_in,
                              void* d_out, int out_size, void* d_ws, size_t ws_size,
                              hipStream_t stream)
{
    static const int NSa[6] = {65536, 16384, 4096, 1024, 256, 64};
    static const int ESa[5] = {1048576, 262144, 65536, 16384, 4096};
    static const int COa[5] = {12, 20, 28, 36, 44};
    static const int CIa[5] = {1, 15, 23, 31, 39};

    const float* x0   = (const float*)d_in[0];
    const float* pos0 = (const float*)d_in[1];

    // ---- workspace layout (words) ----
    int* wsw = (int*)d_ws;
    size_t off = 0;
    auto alw = [&](size_t n) -> size_t {
        size_t p = off; off += (n + 63) & ~(size_t)63; return p;
    };
    size_t degO[5], cdegO[5];
    for (int l = 2; l < 5; l++) degO[l]  = alw(NSa[l]);
    for (int l = 0; l < 5; l++) cdegO[l] = alw(NSa[l + 1]);
    size_t HO = alw(100);
    size_t zeroWords = off;                               // zero-init to here
    size_t rpO[5], crpO[5], eidO[5], cnidO[5];
    rpO[1] = alw(NSa[1] + 1);                             // rp1 (written by bucket1)
    for (int l = 2; l < 5; l++) rpO[l]  = alw(NSa[l] + 1);
    for (int l = 0; l < 5; l++) crpO[l] = alw(NSa[l + 1] + 1);
    for (int l = 2; l < 5; l++) eidO[l] = alw(ESa[l]);
    for (int l = 0; l < 5; l++) cnidO[l] = alw(NSa[l]);
    size_t tsO  = alw(64);
    size_t toO  = alw(64);
    size_t MO   = alw((size_t)TILES0 * NB0);
    size_t M2O  = alw((size_t)TILES0 * NB0);
    size_t ctO  = alw(NB0);
    size_t bsO  = alw(NB0 + 1);
    size_t payO = alw((size_t)ESa[0] * 4);                // seg0 16B records
    size_t M1O  = alw((size_t)TILES1 * NB1);
    size_t M21O = alw((size_t)TILES1 * NB1);
    size_t ct1O = alw(NB1);
    size_t bs1O = alw(NB1 + 1);
    size_t pay1O = alw((size_t)ESa[1] * 4);               // seg1 16B records
    size_t rec1O = alw((size_t)ESa[1] * 4);               // seg1 sorted records
    size_t yO   = alw((size_t)65536 * 12);
    size_t sqO  = alw(8);
    size_t xnO[5], pnO[5];
    for (int l = 0; l < 5; l++) xnO[l] = alw((size_t)NSa[l + 1] * (COa[l] + 3));
    for (int l = 0; l < 5; l++) pnO[l] = alw((size_t)NSa[l] * 3 / 4 + 64);
    // (pn sized generously; actual need NSa[l+1]*3)
    for (int l = 0; l < 5; l++) pnO[l] = alw((size_t)NSa[l + 1] * 3);

    hipMemsetAsync(d_ws, 0, zeroWords * 4, stream);

    // ---- segs 2-9 descriptor (edge segs 2-4 + cluster segs 0-4) ----
    SegArgs sa{};
    int nseg = 0;
    for (int l = 2; l < 5; l++) {
        sa.idx[nseg] = (const int*)d_in[3 + 10 * l];
        sa.cnt[nseg] = wsw + degO[l];
        sa.rp [nseg] = wsw + rpO[l];
        sa.out[nseg] = wsw + eidO[l];
        sa.n  [nseg] = ESa[l];
        sa.nb [nseg] = NSa[l];
        nseg++;
    }
    for (int l = 0; l < 5; l++) {
        sa.idx[nseg] = (const int*)d_in[5 + 10 * l];
        sa.cnt[nseg] = wsw + cdegO[l];
        sa.rp [nseg] = wsw + crpO[l];
        sa.out[nseg] = wsw + cnidO[l];
        sa.n  [nseg] = NSa[l];
        sa.nb [nseg] = NSa[l + 1];
        nseg++;
    }
    ScanAux sx{};
    int tiles = 0, btiles = 0;
    for (int s = 0; s < nseg; s++) {
        sa.tstart[s] = tiles;
        tiles += (sa.n[s] + 1023) / 1024;
        sx.sstart[s] = btiles;
        btiles += (sa.nb[s] + 4095) / 4096;
    }
    for (int s = nseg; s <= 10; s++) {
        sa.tstart[s] = tiles;
        sx.sstart[s] = btiles;
        if (s < 10) {
            sa.idx[s] = sa.idx[nseg - 1]; sa.cnt[s] = sa.cnt[nseg - 1];
            sa.rp[s] = sa.rp[nseg - 1];   sa.out[s] = sa.out[nseg - 1];
            sa.n[s] = 0; sa.nb[s] = 8;
        }
    }
    sx.T = btiles;
    sx.tilesum = wsw + tsO;
    sx.tileoff = wsw + toO;

    float4* pay2 = (float4*)(wsw + payO);
    float4* pay1 = (float4*)(wsw + pay1O);
    float4* rec1 = (float4*)(wsw + rec1O);
    float*  Hp   = (float*)(wsw + HO);

    HArgs ha{};
    int bs = 0;
    ha.bstart[0] = 0;
    ha.eattr[0] = (const float*)d_in[4];
    ha.w1[0] = (const float*)d_in[6];
    ha.b1[0] = (const float*)d_in[7];
    ha.E[0] = 0;
    for (int l = 1; l < 5; l++) {
        ha.eattr[l] = (const float*)d_in[4 + 10 * l];
        ha.w1[l]    = (const float*)d_in[6 + 10 * l];
        ha.b1[l]    = (const float*)d_in[7 + 10 * l];
        ha.E[l]     = ESa[l];
        ha.bstart[l] = bs;
        bs += (ESa[l] + 2047) / 2048;
    }
    ha.bstart[5] = bs;
    ha.H = Hp;

    WArgs wa{};
    for (int l = 0; l < 5; l++) {
        wa.w2[l]   = (const float*)d_in[8 + 10 * l];
        wa.b2[l]   = (const float*)d_in[9 + 10 * l];
        wa.cico[l] = CIa[l] * COa[l];
        wa.E[l]    = ESa[l];
    }
    wa.H  = Hp;
    wa.sq = (float*)(wsw + sqO);

    // ---- K2: cnt0 | cnt1 | hstats | hist ----
    countA_k<<<TILES0 + TILES1 + bs + tiles, 256, 0, stream>>>(
        sa, ha, (const int*)d_in[3], (const int*)d_in[13],
        wsw + MO, wsw + M1O, bs);
    // ---- K3: colscan0 | colscan1 | scanA ----
    scanP1_k<<<NB0 + NB1 + btiles, 256, 0, stream>>>(
        sa, sx, wsw + MO, wsw + M2O, wsw + ctO,
        wsw + M1O, wsw + M21O, wsw + ct1O);
    // ---- K4: bktscan0 | scanB | bktscan1 ----
    scanP2_k<<<3, 512, 0, stream>>>(sa, sx, wsw + ctO, wsw + bsO,
                                    wsw + ct1O, wsw + bs1O);
    // ---- K5: part0 | part1 | scanC ----
    scanP3_k<<<TILES0 + TILES1 + btiles, 256, 0, stream>>>(
        sa, sx,
        (const int*)d_in[2], (const int*)d_in[3], (const float*)d_in[4],
        x0, wsw + M2O, wsw + bsO, pay2,
        (const float*)d_in[6], (const float*)d_in[7], Hp,
        (const int*)d_in[12], (const int*)d_in[13], (const float*)d_in[14],
        wsw + M21O, wsw + bs1O, pay1);

    float* yb = (float*)(wsw + yO);

    // ---- K6: conv0c | bucket1 | wstats | scatter ----
    scatC_k<<<NB0 + NB1 + 5 + tiles, 256, 0, stream>>>(
        sa, wa, pay2, wsw + bsO,
        (const float*)d_in[8], (const float*)d_in[9],
        (const float*)d_in[10], (const float*)d_in[11], x0, yb,
        pay1, wsw + bs1O, wsw + rpO[1], rec1);

    pool_k<12><<<(NSa[1] * 15 + 255) / 256, 256, 0, stream>>>(
        NSa[1], wsw + crpO[0], wsw + cnidO[0], yb, pos0,
        (float*)(wsw + xnO[0]), (float*)(wsw + pnO[0]));

    // ---- level 1: streaming conv ----
    conv1s_k<<<NSa[1], 256, 0, stream>>>(
        wsw + rpO[1], rec1,
        (const float*)d_in[16], (const float*)d_in[17],
        (const float*)d_in[18], (const float*)d_in[19],
        (const float*)d_in[20], (const float*)d_in[21],
        (const float*)(wsw + xnO[0]), yb);
    pool_k<20><<<(NSa[2] * 23 + 255) / 256, 256, 0, stream>>>(
        NSa[2], wsw + crpO[1], wsw + cnidO[1], yb,
        (const float*)(wsw + pnO[0]),
        (float*)(wsw + xnO[1]), (float*)(wsw + pnO[1]));

    // ---- levels 2-4 ----
#define LVLC(l, CI_, CO_) do {                                                 \
    const float* xin   = (const float*)(wsw + xnO[(l) - 1]);                   \
    const float* posin = (const float*)(wsw + pnO[(l) - 1]);                   \
    int N = NSa[(l)], NN = NSa[(l) + 1];                                       \
    coop_conv_k<CI_, CO_><<<N, 256, 0, stream>>>(                              \
        wsw + rpO[(l)], wsw + eidO[(l)],                                       \
        (const int*)d_in[2 + 10 * (l)], (const float*)d_in[4 + 10 * (l)],      \
        (const float*)d_in[6 + 10 * (l)], (const float*)d_in[7 + 10 * (l)],    \
        (const float*)d_in[8 + 10 * (l)], (const float*)d_in[9 + 10 * (l)],    \
        (const float*)d_in[10 + 10 * (l)], (const float*)d_in[11 + 10 * (l)],  \
        xin, yb);                                                              \
    pool_k<CO_><<<(NN * ((CO_) + 3) + 255) / 256, 256, 0, stream>>>(           \
        NN, wsw + crpO[(l)], wsw + cnidO[(l)], yb, posin,                      \
        (float*)(wsw + xnO[(l)]), (float*)(wsw + pnO[(l)]));                   \
} while (0)

    LVLC(2, 23, 28);
    LVLC(3, 31, 36);
    LVLC(4, 39, 44);
#undef LVLC

    fc_k<<<1, 128, 0, stream>>>((const float*)(wsw + xnO[4]),
                                (const float*)d_in[52], (const float*)d_in[53],
                                wa.sq, (float*)d_out);
}